// Round 2
// baseline (853.594 us; speedup 1.0000x reference)
//
#include <hip/hip_runtime.h>

#define B_TOTAL 262144
#define D_IN 512
#define LN_EPS 1e-5f

typedef __attribute__((ext_vector_type(8))) short short8;
typedef __attribute__((ext_vector_type(4))) float f32x4;

__device__ __forceinline__ unsigned short f2bf_rne(float f) {
    union { float f; unsigned int u; } c; c.f = f;
    unsigned int u = c.u;
    u += 0x7fffu + ((u >> 16) & 1u);   // round-to-nearest-even
    return (unsigned short)(u >> 16);
}

__device__ __forceinline__ short8 cvt8(f32x4 lo, f32x4 hi) {
    short8 r;
    r[0] = (short)f2bf_rne(lo[0]); r[1] = (short)f2bf_rne(lo[1]);
    r[2] = (short)f2bf_rne(lo[2]); r[3] = (short)f2bf_rne(lo[3]);
    r[4] = (short)f2bf_rne(hi[0]); r[5] = (short)f2bf_rne(hi[1]);
    r[6] = (short)f2bf_rne(hi[2]); r[7] = (short)f2bf_rne(hi[3]);
    return r;
}

__global__ __launch_bounds__(256) void faiia_kernel(
    const float* __restrict__ x,       // [B, 512] fp32
    const float* __restrict__ mprob,   // [B]
    const float* __restrict__ Wq,      // [32, 512]
    const float* __restrict__ bq,      // [32]
    const float* __restrict__ pk,      // [4, 32]
    const float* __restrict__ pv,      // [4, 32]
    const float* __restrict__ imp,     // [4]
    const float* __restrict__ falpha,  // [1]
    const float* __restrict__ ftemp,   // [1]
    const float* __restrict__ Wo,      // [32, 32]
    const float* __restrict__ bo,      // [32]
    const float* __restrict__ gamma,   // [32]
    const float* __restrict__ beta,    // [32]
    float* __restrict__ out)           // [B*32] out ++ [B*4] weights, fp32
{
    __shared__ float lds_q[64][33];    // pitch 33: conflict-free tail reads
    __shared__ float lds_att[64][33];

    const int tid  = threadIdx.x;
    const int wave = tid >> 6;
    const int lane = tid & 63;
    const int blockBase = blockIdx.x * 64;

    // ================= MFMA projection: q = x @ Wq^T =================
    // mfma_f32_16x16x32_bf16 fragment layouts (HW-verified, learn_hip m89/m120):
    //   A[m = lane&15][k = quad*8 + j]      j=0..7
    //   B[k = quad*8 + j][n = lane&15]      == Wq[n][k] row-major, 8 contiguous k
    //   D[row = quad*4 + reg][col = lane&15] (row=sample, col=att dim)
    const int m    = lane & 15;
    const int quad = lane >> 4;
    const int row  = blockBase + wave * 16 + m;

    const float* ax  = x  + (size_t)row * D_IN + quad * 8;
    const float* bw0 = Wq + (size_t)m   * D_IN + quad * 8;  // n = lane&15
    const float* bw1 = bw0 + 16 * D_IN;                      // n = lane&15 + 16

    f32x4 acc0 = {0.f, 0.f, 0.f, 0.f};
    f32x4 acc1 = {0.f, 0.f, 0.f, 0.f};
    #pragma unroll
    for (int kk = 0; kk < 16; ++kk) {
        f32x4 a0 = *(const f32x4*)(ax  + kk * 32);
        f32x4 a1 = *(const f32x4*)(ax  + kk * 32 + 4);
        f32x4 p0 = *(const f32x4*)(bw0 + kk * 32);
        f32x4 p1 = *(const f32x4*)(bw0 + kk * 32 + 4);
        f32x4 r0 = *(const f32x4*)(bw1 + kk * 32);
        f32x4 r1 = *(const f32x4*)(bw1 + kk * 32 + 4);
        short8 a  = cvt8(a0, a1);
        short8 b0 = cvt8(p0, p1);
        short8 b1 = cvt8(r0, r1);
        acc0 = __builtin_amdgcn_mfma_f32_16x16x32_bf16(a, b0, acc0, 0, 0, 0);
        acc1 = __builtin_amdgcn_mfma_f32_16x16x32_bf16(a, b1, acc1, 0, 0, 0);
    }

    {
        const float bq0 = bq[m];
        const float bq1 = bq[m + 16];
        #pragma unroll
        for (int r = 0; r < 4; ++r) {
            int s = wave * 16 + quad * 4 + r;   // local sample index (D-row)
            lds_q[s][m]      = acc0[r] + bq0;
            lds_q[s][m + 16] = acc1[r] + bq1;
        }
    }
    __syncthreads();

    // ================= per-sample tail: 4 threads / sample, fp32 exact =====
    const int sLocal = tid >> 2;       // 0..63
    const int part   = tid & 3;        // owns dims part*8 .. part*8+7
    const int d0     = part * 8;
    const int sample = blockBase + sLocal;

    float q8[8];
    #pragma unroll
    for (int j = 0; j < 8; ++j) q8[j] = lds_q[sLocal][d0 + j];

    // scores = q @ pk^T + importance   (reduce partials over the 4-lane group)
    float sc[4];
    #pragma unroll
    for (int p = 0; p < 4; ++p) {
        float s = 0.f;
        #pragma unroll
        for (int j = 0; j < 8; ++j) s += q8[j] * pk[p * 32 + d0 + j];
        s += __shfl_xor(s, 1);
        s += __shfl_xor(s, 2);
        sc[p] = s + imp[p];
    }

    // focal modulation (GAMMA=2 -> square)
    const float prob = mprob[sample];
    const float unc  = 1.f - fabsf(prob - 0.5f) * 2.f;
    const float ue   = unc + 1e-8f;
    const float fw   = falpha[0] * ue * ue * ftemp[0];
    const float SCALE = 0.1767766952966369f;   // 32^-0.5
    const float mult  = (1.f + fw) * SCALE;

    // softmax over 4 prototypes
    float z[4];
    #pragma unroll
    for (int p = 0; p < 4; ++p) z[p] = sc[p] * mult;
    float zmax = fmaxf(fmaxf(z[0], z[1]), fmaxf(z[2], z[3]));
    float w[4], wsum = 0.f;
    #pragma unroll
    for (int p = 0; p < 4; ++p) { w[p] = expf(z[p] - zmax); wsum += w[p]; }
    const float winv = 1.f / wsum;
    #pragma unroll
    for (int p = 0; p < 4; ++p) w[p] *= winv;

    // attended = weights @ proto_values  (our 8 dims), broadcast through LDS
    #pragma unroll
    for (int j = 0; j < 8; ++j) {
        float a = 0.f;
        #pragma unroll
        for (int p = 0; p < 4; ++p) a += w[p] * pv[p * 32 + d0 + j];
        lds_att[sLocal][d0 + j] = a;
    }
    __syncthreads();

    float att[32];
    #pragma unroll
    for (int n = 0; n < 32; ++n) att[n] = lds_att[sLocal][n];

    // out = attended @ Wo^T + bo   (our 8 output dims)
    float o[8];
    #pragma unroll
    for (int jo = 0; jo < 8; ++jo) {
        const int n2 = d0 + jo;
        float s = bo[n2];
        #pragma unroll
        for (int n = 0; n < 32; ++n) s += att[n] * Wo[n2 * 32 + n];
        o[jo] = s;
    }

    // LayerNorm over 32 dims (population var), partials reduced over 4 lanes
    float s1 = 0.f, s2 = 0.f;
    #pragma unroll
    for (int jo = 0; jo < 8; ++jo) { s1 += o[jo]; s2 += o[jo] * o[jo]; }
    s1 += __shfl_xor(s1, 1); s1 += __shfl_xor(s1, 2);
    s2 += __shfl_xor(s2, 1); s2 += __shfl_xor(s2, 2);
    const float mu   = s1 * (1.f / 32.f);
    const float var  = s2 * (1.f / 32.f) - mu * mu;
    const float rstd = rsqrtf(var + LN_EPS);

    f32x4 res_lo, res_hi;
    #pragma unroll
    for (int jo = 0; jo < 8; ++jo) {
        const int n2 = d0 + jo;
        float y = (o[jo] - mu) * rstd * gamma[n2] + beta[n2];
        if (jo < 4) res_lo[jo] = y; else res_hi[jo - 4] = y;
    }
    // 32 B coalesced store per thread (two float4)
    *(f32x4*)(out + (size_t)sample * 32 + d0)     = res_lo;
    *(f32x4*)(out + (size_t)sample * 32 + d0 + 4) = res_hi;

    if (part == 0) {
        f32x4 wres;
        #pragma unroll
        for (int p = 0; p < 4; ++p) wres[p] = w[p];
        *(f32x4*)(out + (size_t)B_TOTAL * 32 + (size_t)sample * 4) = wres;
    }
}

extern "C" void kernel_launch(void* const* d_in, const int* in_sizes, int n_in,
                              void* d_out, int out_size, void* d_ws, size_t ws_size,
                              hipStream_t stream) {
    const float* x      = (const float*)d_in[0];
    const float* mprob  = (const float*)d_in[1];
    const float* Wq     = (const float*)d_in[2];
    const float* bq     = (const float*)d_in[3];
    const float* pk     = (const float*)d_in[4];
    const float* pv     = (const float*)d_in[5];
    const float* imp    = (const float*)d_in[6];
    const float* falpha = (const float*)d_in[7];
    const float* ftemp  = (const float*)d_in[8];
    const float* Wo     = (const float*)d_in[9];
    const float* bo     = (const float*)d_in[10];
    const float* gamma  = (const float*)d_in[11];
    const float* beta   = (const float*)d_in[12];
    float* out = (float*)d_out;

    const int blocks = B_TOTAL / 64;   // 4096 blocks, 64 samples each
    faiia_kernel<<<blocks, 256, 0, stream>>>(
        x, mprob, Wq, bq, pk, pv, imp, falpha, ftemp, Wo, bo, gamma, beta, out);
}